// Round 1
// baseline (2267.523 us; speedup 1.0000x reference)
//
#include <hip/hip_runtime.h>
#include <math.h>

#define DD 64
#define INV_TEMP 4.0f   // 1 / C_TEMP, C_TEMP = 0.25

__device__ __forceinline__ float waveSum(float x) {
#pragma unroll
    for (int off = 32; off > 0; off >>= 1) x += __shfl_xor(x, off, 64);
    return x;
}

// out[row[e]*D + lane] += val[e] * feat[col[e]][lane]
// feat is the concatenation [fa ; fb] split at `split` rows.
__global__ void spmm_kernel(
    const int* __restrict__ row, const int* __restrict__ col,
    const float* __restrict__ val,
    const float* __restrict__ fa, const float* __restrict__ fb, int split,
    float* __restrict__ out, int nE)
{
    int lane = threadIdx.x & 63;
    int wave = (blockIdx.x * blockDim.x + threadIdx.x) >> 6;
    int nW   = (gridDim.x * blockDim.x) >> 6;
    for (int e = wave; e < nE; e += nW) {
        int r = row[e];
        int c = col[e];
        float v = val[e];
        const float* src = (c < split) ? (fa + (size_t)c * DD)
                                       : (fb + (size_t)(c - split) * DD);
        atomicAdd(out + (size_t)r * DD + lane, v * src[lane]);
    }
}

// acc[r] = f0[r] + g[r]/max(||g[r]||,eps) + h[r]/max(||h[r]||,eps)
// acc may alias g (each (row,lane) reads before writing its own address).
__global__ void finalize_kernel(
    const float* __restrict__ fa, const float* __restrict__ fb, int split,
    const float* __restrict__ g, const float* __restrict__ h,
    float* __restrict__ acc, int n)
{
    int lane = threadIdx.x & 63;
    int wave = (blockIdx.x * blockDim.x + threadIdx.x) >> 6;
    int nW   = (gridDim.x * blockDim.x) >> 6;
    for (int r = wave; r < n; r += nW) {
        float f0 = (r < split) ? fa[(size_t)r * DD + lane]
                               : fb[(size_t)(r - split) * DD + lane];
        float gv = g[(size_t)r * DD + lane];
        float hv = h[(size_t)r * DD + lane];
        float ng = sqrtf(waveSum(gv * gv));
        float nh = sqrtf(waveSum(hv * hv));
        acc[(size_t)r * DD + lane] = f0 + gv / fmaxf(ng, 1e-12f)
                                        + hv / fmaxf(nh, 1e-12f);
    }
}

// Per batch row: BPR softplus term + write L2-normalized pos/aug rows for c-loss.
__global__ void batch_kernel(
    const int* __restrict__ users, const int* __restrict__ bundles,
    const float* __restrict__ IL, const float* __restrict__ ILb,
    const float* __restrict__ BL, int NUv,
    float* __restrict__ pos1, float* __restrict__ aug1,
    float* __restrict__ pos2, float* __restrict__ aug2,
    float* __restrict__ sums, int batch)
{
    int lane = threadIdx.x & 63;
    int wave = (blockIdx.x * blockDim.x + threadIdx.x) >> 6;
    int nW   = (gridDim.x * blockDim.x) >> 6;
    for (int b = wave; b < batch; b += nW) {
        int u   = users[b];
        int bp  = bundles[2 * b];
        int bn  = bundles[2 * b + 1];
        float ilu  = IL [(size_t)u * DD + lane];
        float blu  = BL [(size_t)u * DD + lane];
        float ilb0 = ILb[(size_t)bp * DD + lane];
        float ilb1 = ILb[(size_t)bn * DD + lane];
        float blb0 = BL [(size_t)(NUv + bp) * DD + lane];
        float blb1 = BL [(size_t)(NUv + bn) * DD + lane];
        float d0 = waveSum(ilu * ilb0 + blu * blb0);   // pred pos
        float d1 = waveSum(ilu * ilb1 + blu * blb1);   // pred neg
        float x  = d1 - d0;
        float sp = fmaxf(x, 0.f) + log1pf(expf(-fabsf(x)));  // softplus, stable
        if (lane == 0) atomicAdd(&sums[0], sp);
        float nilu = sqrtf(waveSum(ilu * ilu));
        float nblu = sqrtf(waveSum(blu * blu));
        float nilb = sqrtf(waveSum(ilb0 * ilb0));
        float nblb = sqrtf(waveSum(blb0 * blb0));
        pos1[(size_t)b * DD + lane] = ilu  / fmaxf(nilu, 1e-12f);
        aug1[(size_t)b * DD + lane] = blu  / fmaxf(nblu, 1e-12f);
        pos2[(size_t)b * DD + lane] = ilb0 / fmaxf(nilb, 1e-12f);
        aug2[(size_t)b * DD + lane] = blb0 / fmaxf(nblb, 1e-12f);
    }
}

// One block per row i: online logsumexp over ttl[i, :] = (pos_n[i] . aug_n[j]) / temp.
// Accumulates (lse - diag) into sums[1 + blockIdx.y].
__global__ void closs_kernel(
    const float* __restrict__ pos1, const float* __restrict__ aug1,
    const float* __restrict__ pos2, const float* __restrict__ aug2,
    float* __restrict__ sums, int batch)
{
    const float* pos = (blockIdx.y == 0) ? pos1 : pos2;
    const float* aug = (blockIdx.y == 0) ? aug1 : aug2;
    float* accum = sums + 1 + blockIdx.y;

    __shared__ float p[DD];
    __shared__ float wm[4], wsm[4], diag;
    int i = blockIdx.x;
    int tid = threadIdx.x, lane = tid & 63, w = tid >> 6;
    if (tid < DD) p[tid] = pos[(size_t)i * DD + tid];
    __syncthreads();

    float m = -1e30f, s = 0.f;
    for (int j = w; j < batch; j += 4) {
        float x = p[lane] * aug[(size_t)j * DD + lane];
        x = waveSum(x);
        float t = x * INV_TEMP;
        if (j == i && lane == 0) diag = t;
        float nm = fmaxf(m, t);
        s = s * expf(m - nm) + expf(t - nm);
        m = nm;
    }
    if (lane == 0) { wm[w] = m; wsm[w] = s; }
    __syncthreads();
    if (tid == 0) {
        float M = fmaxf(fmaxf(wm[0], wm[1]), fmaxf(wm[2], wm[3]));
        float S = wsm[0] * expf(wm[0] - M) + wsm[1] * expf(wm[1] - M)
                + wsm[2] * expf(wm[2] - M) + wsm[3] * expf(wm[3] - M);
        float lse = M + logf(S);
        atomicAdd(accum, lse - diag);
    }
}

__global__ void final_kernel(const float* __restrict__ sums,
                             float* __restrict__ out, float invB)
{
    if (threadIdx.x == 0 && blockIdx.x == 0) {
        out[0] = sums[0] * invB;                       // bpr mean
        out[1] = 0.5f * (sums[1] + sums[2]) * invB;    // c_loss
    }
}

extern "C" void kernel_launch(void* const* d_in, const int* in_sizes, int n_in,
                              void* d_out, int out_size, void* d_ws, size_t ws_size,
                              hipStream_t stream)
{
    const float* usersF = (const float*)d_in[0];
    const float* itemsF = (const float*)d_in[1];
    const float* bundF  = (const float*)d_in[2];
    const int*   il_row = (const int*)d_in[3];
    const int*   il_col = (const int*)d_in[4];
    const float* il_val = (const float*)d_in[5];
    const int*   bl_row = (const int*)d_in[6];
    const int*   bl_col = (const int*)d_in[7];
    const float* bl_val = (const float*)d_in[8];
    const int*   agg_row = (const int*)d_in[9];
    const int*   agg_col = (const int*)d_in[10];
    const float* agg_val = (const float*)d_in[11];
    const int*   users   = (const int*)d_in[12];
    const int*   bundles = (const int*)d_in[13];

    const int NUv = in_sizes[0] / DD;
    const int NIv = in_sizes[1] / DD;
    const int NBv = in_sizes[2] / DD;
    const int E1 = in_sizes[3], E2 = in_sizes[6], E3 = in_sizes[9];
    const int batch = in_sizes[12];
    const int n1 = NUv + NIv;   // item-level graph nodes
    const int n2 = NUv + NBv;   // bundle-level graph nodes

    float* ws = (float*)d_ws;
    size_t off = 0;
    float* sums = ws;            off += 16;             // [bpr, c1, c2, ...]
    float* b0   = ws + off;      off += (size_t)n1 * DD; // g_item -> IL acc
    float* b1   = ws + off;      off += (size_t)n1 * DD; // h_item -> g_bundle -> BL acc
    float* b2   = ws + off;      off += (size_t)n2 * DD; // h_bundle
    float* ILbB = ws + off;      off += (size_t)NBv * DD;
    float* pos1 = ws + off;      off += (size_t)batch * DD;
    float* aug1 = ws + off;      off += (size_t)batch * DD;
    float* pos2 = ws + off;      off += (size_t)batch * DD;
    float* aug2 = ws + off;      off += (size_t)batch * DD;

    auto spmmBlocks = [](int E) { int w = (E + 3) / 4; return w > 16384 ? 16384 : w; };

    hipMemsetAsync(sums, 0, 16 * sizeof(float), stream);

    // ---- item-level propagation over (U+I) graph ----
    hipMemsetAsync(b0, 0, (size_t)n1 * DD * sizeof(float), stream);
    spmm_kernel<<<spmmBlocks(E1), 256, 0, stream>>>(
        il_row, il_col, il_val, usersF, itemsF, NUv, b0, E1);
    hipMemsetAsync(b1, 0, (size_t)n1 * DD * sizeof(float), stream);
    spmm_kernel<<<spmmBlocks(E1), 256, 0, stream>>>(
        il_row, il_col, il_val, b0, b0, n1, b1, E1);
    finalize_kernel<<<(n1 + 3) / 4, 256, 0, stream>>>(
        usersF, itemsF, NUv, b0, b1, b0, n1);          // IL acc -> b0

    // ---- bundle rep from items: IL_b = agg @ IL_i ----
    hipMemsetAsync(ILbB, 0, (size_t)NBv * DD * sizeof(float), stream);
    spmm_kernel<<<spmmBlocks(E3), 256, 0, stream>>>(
        agg_row, agg_col, agg_val,
        b0 + (size_t)NUv * DD, b0 + (size_t)NUv * DD, NIv + 1, ILbB, E3);

    // ---- bundle-level propagation over (U+B) graph ----
    hipMemsetAsync(b1, 0, (size_t)n2 * DD * sizeof(float), stream);
    spmm_kernel<<<spmmBlocks(E2), 256, 0, stream>>>(
        bl_row, bl_col, bl_val, usersF, bundF, NUv, b1, E2);
    hipMemsetAsync(b2, 0, (size_t)n2 * DD * sizeof(float), stream);
    spmm_kernel<<<spmmBlocks(E2), 256, 0, stream>>>(
        bl_row, bl_col, bl_val, b1, b1, n2, b2, E2);
    finalize_kernel<<<(n2 + 3) / 4, 256, 0, stream>>>(
        usersF, bundF, NUv, b1, b2, b1, n2);           // BL acc -> b1

    // ---- batch: BPR + normalized gathers ----
    batch_kernel<<<(batch + 3) / 4, 256, 0, stream>>>(
        users, bundles, b0, ILbB, b1, NUv,
        pos1, aug1, pos2, aug2, sums, batch);

    // ---- contrastive loss: two 2048x2048 online-logsumexp passes ----
    dim3 cg(batch, 2);
    closs_kernel<<<cg, 256, 0, stream>>>(pos1, aug1, pos2, aug2, sums, batch);

    final_kernel<<<1, 1, 0, stream>>>(sums, (float*)d_out, 1.0f / (float)batch);
}

// Round 2
// 1083.725 us; speedup vs baseline: 2.0923x; 2.0923x over previous
//
#include <hip/hip_runtime.h>
#include <math.h>

#define DD 64
#define INV_TEMP 4.0f   // 1 / C_TEMP, C_TEMP = 0.25

__device__ __forceinline__ float waveSum(float x) {
#pragma unroll
    for (int off = 32; off > 0; off >>= 1) x += __shfl_xor(x, off, 64);
    return x;
}

// ------------------------- CSR build -------------------------

__global__ void hist_kernel(const int* __restrict__ row, int* __restrict__ cnt, int nE) {
    int i = blockIdx.x * blockDim.x + threadIdx.x;
    int stride = gridDim.x * blockDim.x;
    for (; i < nE; i += stride) atomicAdd(&cnt[row[i]], 1);
}

// 1024-element chunks, 256 threads x 4. In-place safe (each elem read/written by owner).
__global__ void scan_chunk(const int* __restrict__ in, int* __restrict__ out,
                           int* __restrict__ blockSums, int n) {
    __shared__ int wtot[4];
    int b = blockIdx.x, t = threadIdx.x;
    int base = b * 1024 + t * 4;
    int v[4];
#pragma unroll
    for (int q = 0; q < 4; q++) v[q] = (base + q < n) ? in[base + q] : 0;
    int s = v[0] + v[1] + v[2] + v[3];
    int lane = t & 63, w = t >> 6;
    int sc = s;
    for (int off = 1; off < 64; off <<= 1) {
        int u = __shfl_up(sc, off, 64);
        if (lane >= off) sc += u;
    }
    if (lane == 63) wtot[w] = sc;
    __syncthreads();
    int woff = 0;
    for (int i = 0; i < w; i++) woff += wtot[i];
    int run = woff + sc - s;  // exclusive prefix for this thread's first elem
#pragma unroll
    for (int q = 0; q < 4; q++) {
        if (base + q < n) out[base + q] = run;
        run += v[q];
    }
    if (t == 255) blockSums[b] = woff + sc;
}

// single block, nb <= 256
__global__ void scan_small(int* __restrict__ bs, int nb) {
    __shared__ int wtot[4];
    int t = threadIdx.x;
    int v = (t < nb) ? bs[t] : 0;
    int lane = t & 63, w = t >> 6;
    int sc = v;
    for (int off = 1; off < 64; off <<= 1) {
        int u = __shfl_up(sc, off, 64);
        if (lane >= off) sc += u;
    }
    if (lane == 63) wtot[w] = sc;
    __syncthreads();
    int woff = 0;
    for (int i = 0; i < w; i++) woff += wtot[i];
    if (t < nb) bs[t] = woff + sc - v;  // exclusive
}

__global__ void scan_add(int* __restrict__ out, const int* __restrict__ bs, int n) {
    int off = bs[blockIdx.x];
    int base = blockIdx.x * 1024 + threadIdx.x;
#pragma unroll
    for (int q = 0; q < 4; q++) {
        int i = base + q * 256;
        if (i < n) out[i] += off;
    }
}

// rp holds exclusive row starts; used as cursors (mutated). After this,
// rp[r] == exclusive_start(r+1), so row r spans [(r? rp[r-1]:0), rp[r]).
__global__ void scatter_kernel(const int* __restrict__ row, const int* __restrict__ col,
                               const float* __restrict__ val,
                               int* __restrict__ rp, int* __restrict__ cs,
                               float* __restrict__ vs, int nE) {
    int i = blockIdx.x * blockDim.x + threadIdx.x;
    int stride = gridDim.x * blockDim.x;
    for (; i < nE; i += stride) {
        int p = atomicAdd(&rp[row[i]], 1);
        cs[p] = col[i];
        vs[p] = val[i];
    }
}

// ------------------------- SpMM -------------------------

// CSR, wave per row, register accumulate, no atomics.
__global__ void spmm_csr_kernel(
    const int* __restrict__ rp, const int* __restrict__ cs, const float* __restrict__ vs,
    const float* __restrict__ fa, const float* __restrict__ fb, int split,
    float* __restrict__ out, int n)
{
    int lane = threadIdx.x & 63;
    int wave = (blockIdx.x * blockDim.x + threadIdx.x) >> 6;
    int nW   = (gridDim.x * blockDim.x) >> 6;
    for (int r = wave; r < n; r += nW) {
        int start = (r == 0) ? 0 : rp[r - 1];
        int end   = rp[r];
        float acc = 0.f;
        int e = start;
        for (; e + 2 <= end; e += 2) {
            int c0 = cs[e], c1 = cs[e + 1];
            float v0 = vs[e], v1 = vs[e + 1];
            const float* s0 = (c0 < split) ? fa + (size_t)c0 * DD : fb + (size_t)(c0 - split) * DD;
            const float* s1 = (c1 < split) ? fa + (size_t)c1 * DD : fb + (size_t)(c1 - split) * DD;
            acc += v0 * s0[lane];
            acc += v1 * s1[lane];
        }
        if (e < end) {
            int c = cs[e];
            const float* s0 = (c < split) ? fa + (size_t)c * DD : fb + (size_t)(c - split) * DD;
            acc += vs[e] * s0[lane];
        }
        out[(size_t)r * DD + lane] = acc;
    }
}

// Fallback: COO + atomics (round-0 path), used only if ws too small for CSR.
__global__ void spmm_kernel(
    const int* __restrict__ row, const int* __restrict__ col,
    const float* __restrict__ val,
    const float* __restrict__ fa, const float* __restrict__ fb, int split,
    float* __restrict__ out, int nE)
{
    int lane = threadIdx.x & 63;
    int wave = (blockIdx.x * blockDim.x + threadIdx.x) >> 6;
    int nW   = (gridDim.x * blockDim.x) >> 6;
    for (int e = wave; e < nE; e += nW) {
        int r = row[e];
        int c = col[e];
        float v = val[e];
        const float* src = (c < split) ? (fa + (size_t)c * DD)
                                       : (fb + (size_t)(c - split) * DD);
        atomicAdd(out + (size_t)r * DD + lane, v * src[lane]);
    }
}

// acc[r] = f0[r] + g[r]/max(||g||,eps) + h[r]/max(||h||,eps); acc may alias g.
__global__ void finalize_kernel(
    const float* __restrict__ fa, const float* __restrict__ fb, int split,
    const float* __restrict__ g, const float* __restrict__ h,
    float* __restrict__ acc, int n)
{
    int lane = threadIdx.x & 63;
    int wave = (blockIdx.x * blockDim.x + threadIdx.x) >> 6;
    int nW   = (gridDim.x * blockDim.x) >> 6;
    for (int r = wave; r < n; r += nW) {
        float f0 = (r < split) ? fa[(size_t)r * DD + lane]
                               : fb[(size_t)(r - split) * DD + lane];
        float gv = g[(size_t)r * DD + lane];
        float hv = h[(size_t)r * DD + lane];
        float ng = sqrtf(waveSum(gv * gv));
        float nh = sqrtf(waveSum(hv * hv));
        acc[(size_t)r * DD + lane] = f0 + gv / fmaxf(ng, 1e-12f)
                                        + hv / fmaxf(nh, 1e-12f);
    }
}

// ------------------------- batch + losses -------------------------

__global__ void batch_kernel(
    const int* __restrict__ users, const int* __restrict__ bundles,
    const float* __restrict__ IL, const float* __restrict__ ILb,
    const float* __restrict__ BL, int NUv,
    float* __restrict__ pos1, float* __restrict__ aug1,
    float* __restrict__ pos2, float* __restrict__ aug2,
    float* __restrict__ sums, int batch)
{
    int lane = threadIdx.x & 63;
    int wave = (blockIdx.x * blockDim.x + threadIdx.x) >> 6;
    int nW   = (gridDim.x * blockDim.x) >> 6;
    for (int b = wave; b < batch; b += nW) {
        int u   = users[b];
        int bp  = bundles[2 * b];
        int bn  = bundles[2 * b + 1];
        float ilu  = IL [(size_t)u * DD + lane];
        float blu  = BL [(size_t)u * DD + lane];
        float ilb0 = ILb[(size_t)bp * DD + lane];
        float ilb1 = ILb[(size_t)bn * DD + lane];
        float blb0 = BL [(size_t)(NUv + bp) * DD + lane];
        float blb1 = BL [(size_t)(NUv + bn) * DD + lane];
        float d0 = waveSum(ilu * ilb0 + blu * blb0);
        float d1 = waveSum(ilu * ilb1 + blu * blb1);
        float x  = d1 - d0;
        float sp = fmaxf(x, 0.f) + log1pf(expf(-fabsf(x)));
        if (lane == 0) atomicAdd(&sums[0], sp);
        float nilu = sqrtf(waveSum(ilu * ilu));
        float nblu = sqrtf(waveSum(blu * blu));
        float nilb = sqrtf(waveSum(ilb0 * ilb0));
        float nblb = sqrtf(waveSum(blb0 * blb0));
        pos1[(size_t)b * DD + lane] = ilu  / fmaxf(nilu, 1e-12f);
        aug1[(size_t)b * DD + lane] = blu  / fmaxf(nblu, 1e-12f);
        pos2[(size_t)b * DD + lane] = ilb0 / fmaxf(nilb, 1e-12f);
        aug2[(size_t)b * DD + lane] = blb0 / fmaxf(nblb, 1e-12f);
    }
}

// Load a 64-row x 64-dim tile transposed into LDS: dst[k*68 + i] = src[(rowBase+i)*64 + k]
__device__ __forceinline__ void load_tile_T(const float* __restrict__ src, int rowBase,
                                            int batch, float* __restrict__ dst, int tx) {
    int i = tx >> 2, c = tx & 3;
#pragma unroll
    for (int t = 0; t < 4; t++) {
        int k0 = c * 4 + t * 16;
        float4 v = make_float4(0.f, 0.f, 0.f, 0.f);
        int gi = rowBase + i;
        if (gi < batch) v = *(const float4*)&src[(size_t)gi * DD + k0];
        dst[(k0 + 0) * 68 + i] = v.x;
        dst[(k0 + 1) * 68 + i] = v.y;
        dst[(k0 + 2) * 68 + i] = v.z;
        dst[(k0 + 3) * 68 + i] = v.w;
    }
}

// Scores bounded: pos/aug unit-norm -> t in [-4,4]; plain sum-of-exp is safe.
// Accumulates S[m*batch + i] += sum_j exp(t_ij) over this block's j-chunk,
// and writes Dg[m*batch + i] = t_ii when the diagonal falls in this block.
__global__ void closs_kernel(
    const float* __restrict__ pos1, const float* __restrict__ aug1,
    const float* __restrict__ pos2, const float* __restrict__ aug2,
    float* __restrict__ S, float* __restrict__ Dg, int batch, int jChunk)
{
    const float* pos = blockIdx.z ? pos2 : pos1;
    const float* aug = blockIdx.z ? aug2 : aug1;
    __shared__ float Pt[64 * 68];
    __shared__ float At[64 * 68];
    __shared__ float red[64 * 17];
    int tx = threadIdx.x;
    int iBase = blockIdx.x * 64;
    int jBeg = blockIdx.y * jChunk;
    int jEnd = min(jBeg + jChunk, batch);
    load_tile_T(pos, iBase, batch, Pt, tx);
    int tr = tx >> 4, tc = tx & 15;
    float rs[4] = {0.f, 0.f, 0.f, 0.f};
    for (int j0 = jBeg; j0 < jEnd; j0 += 64) {
        __syncthreads();
        load_tile_T(aug, j0, batch, At, tx);
        __syncthreads();
        float acc[16];
#pragma unroll
        for (int q = 0; q < 16; q++) acc[q] = 0.f;
#pragma unroll 8
        for (int k = 0; k < 64; k++) {
            float4 pv = *(const float4*)&Pt[k * 68 + 4 * tr];
            float4 av = *(const float4*)&At[k * 68 + 4 * tc];
            acc[0]  += pv.x * av.x;  acc[1]  += pv.x * av.y;
            acc[2]  += pv.x * av.z;  acc[3]  += pv.x * av.w;
            acc[4]  += pv.y * av.x;  acc[5]  += pv.y * av.y;
            acc[6]  += pv.y * av.z;  acc[7]  += pv.y * av.w;
            acc[8]  += pv.z * av.x;  acc[9]  += pv.z * av.y;
            acc[10] += pv.z * av.z;  acc[11] += pv.z * av.w;
            acc[12] += pv.w * av.x;  acc[13] += pv.w * av.y;
            acc[14] += pv.w * av.z;  acc[15] += pv.w * av.w;
        }
#pragma unroll
        for (int qi = 0; qi < 4; qi++) {
            int gi = iBase + 4 * tr + qi;
#pragma unroll
            for (int qj = 0; qj < 4; qj++) {
                int gj = j0 + 4 * tc + qj;
                float t = acc[qi * 4 + qj] * INV_TEMP;
                if (gi < batch && gj < batch) {
                    rs[qi] += __expf(t);
                    if (gi == gj) Dg[blockIdx.z * batch + gi] = t;
                }
            }
        }
    }
    __syncthreads();
#pragma unroll
    for (int qi = 0; qi < 4; qi++) red[(4 * tr + qi) * 17 + tc] = rs[qi];
    __syncthreads();
    if (tx < 64) {
        float s = 0.f;
#pragma unroll
        for (int c = 0; c < 16; c++) s += red[tx * 17 + c];
        int gi = iBase + tx;
        if (gi < batch) atomicAdd(&S[blockIdx.z * batch + gi], s);
    }
}

__global__ void closs_finish(const float* __restrict__ S, const float* __restrict__ Dg,
                             float* __restrict__ sums, int batch)
{
    int m = blockIdx.x;  // 0 or 1
    int tid = threadIdx.x;
    float local = 0.f;
    for (int i = tid; i < batch; i += blockDim.x)
        local += logf(S[m * batch + i]) - Dg[m * batch + i];
    local = waveSum(local);
    __shared__ float wsm[4];
    if ((tid & 63) == 0) wsm[tid >> 6] = local;
    __syncthreads();
    if (tid == 0) sums[1 + m] = wsm[0] + wsm[1] + wsm[2] + wsm[3];
}

__global__ void final_kernel(const float* __restrict__ sums,
                             float* __restrict__ out, float invB)
{
    if (threadIdx.x == 0 && blockIdx.x == 0) {
        out[0] = sums[0] * invB;                       // bpr mean
        out[1] = 0.5f * (sums[1] + sums[2]) * invB;    // c_loss
    }
}

// ------------------------- driver -------------------------

static inline void build_csr(const int* row, const int* col, const float* val,
                             int* rp, int* cs, float* vs, int* bsum,
                             int n, int E, hipStream_t stream)
{
    hipMemsetAsync(rp, 0, (size_t)n * sizeof(int), stream);
    int hb = (E + 255) / 256; if (hb > 8192) hb = 8192;
    hist_kernel<<<hb, 256, 0, stream>>>(row, rp, E);
    int nb = (n + 1023) / 1024;
    scan_chunk<<<nb, 256, 0, stream>>>(rp, rp, bsum, n);
    scan_small<<<1, 256, 0, stream>>>(bsum, nb);
    scan_add<<<nb, 256, 0, stream>>>(rp, bsum, n);
    scatter_kernel<<<hb, 256, 0, stream>>>(row, col, val, rp, cs, vs, E);
}

extern "C" void kernel_launch(void* const* d_in, const int* in_sizes, int n_in,
                              void* d_out, int out_size, void* d_ws, size_t ws_size,
                              hipStream_t stream)
{
    const float* usersF = (const float*)d_in[0];
    const float* itemsF = (const float*)d_in[1];
    const float* bundF  = (const float*)d_in[2];
    const int*   il_row = (const int*)d_in[3];
    const int*   il_col = (const int*)d_in[4];
    const float* il_val = (const float*)d_in[5];
    const int*   bl_row = (const int*)d_in[6];
    const int*   bl_col = (const int*)d_in[7];
    const float* bl_val = (const float*)d_in[8];
    const int*   agg_row = (const int*)d_in[9];
    const int*   agg_col = (const int*)d_in[10];
    const float* agg_val = (const float*)d_in[11];
    const int*   users   = (const int*)d_in[12];
    const int*   bundles = (const int*)d_in[13];

    const int NUv = in_sizes[0] / DD;
    const int NIv = in_sizes[1] / DD;
    const int NBv = in_sizes[2] / DD;
    const int E1 = in_sizes[3], E2 = in_sizes[6], E3 = in_sizes[9];
    const int batch = in_sizes[12];
    const int n1 = NUv + NIv;
    const int n2 = NUv + NBv;

    float* ws = (float*)d_ws;
    size_t off = 0;
    float* sums = ws + off;      off += 16;
    float* S    = ws + off;      off += (size_t)2 * batch;
    float* Dg   = ws + off;      off += (size_t)2 * batch;
    float* b0   = ws + off;      off += (size_t)n1 * DD;
    float* b1   = ws + off;      off += (size_t)n1 * DD;
    float* b2   = ws + off;      off += (size_t)n2 * DD;
    float* ILbB = ws + off;      off += (size_t)NBv * DD;
    float* pos1 = ws + off;      off += (size_t)batch * DD;
    float* aug1 = ws + off;      off += (size_t)batch * DD;
    float* pos2 = ws + off;      off += (size_t)batch * DD;
    float* aug2 = ws + off;      off += (size_t)batch * DD;
    // CSR region (only touched if it fits)
    int*   bsum = (int*)(ws + off);   off += 256;
    int*   rp1  = (int*)(ws + off);   off += (size_t)n1;
    int*   cs1  = (int*)(ws + off);   off += (size_t)E1;
    float* vs1  = ws + off;           off += (size_t)E1;
    int*   rp2  = (int*)(ws + off);   off += (size_t)n2;
    int*   cs2  = (int*)(ws + off);   off += (size_t)E2;
    float* vs2  = ws + off;           off += (size_t)E2;
    int*   rp3  = (int*)(ws + off);   off += (size_t)NBv;
    int*   cs3  = (int*)(ws + off);   off += (size_t)E3;
    float* vs3  = ws + off;           off += (size_t)E3;
    const bool useCSR = (off * sizeof(float) <= ws_size);

    hipMemsetAsync(sums, 0, 16 * sizeof(float), stream);
    hipMemsetAsync(S, 0, (size_t)2 * batch * sizeof(float), stream);

    auto spmmBlocks = [](int E) { int w = (E + 3) / 4; return w > 16384 ? 16384 : w; };

    if (useCSR) {
        build_csr(il_row, il_col, il_val, rp1, cs1, vs1, bsum, n1, E1, stream);
        build_csr(bl_row, bl_col, bl_val, rp2, cs2, vs2, bsum, n2, E2, stream);
        build_csr(agg_row, agg_col, agg_val, rp3, cs3, vs3, bsum, NBv, E3, stream);

        // item-level propagation
        spmm_csr_kernel<<<(n1 + 3) / 4, 256, 0, stream>>>(
            rp1, cs1, vs1, usersF, itemsF, NUv, b0, n1);
        spmm_csr_kernel<<<(n1 + 3) / 4, 256, 0, stream>>>(
            rp1, cs1, vs1, b0, b0, n1, b1, n1);
        finalize_kernel<<<(n1 + 3) / 4, 256, 0, stream>>>(
            usersF, itemsF, NUv, b0, b1, b0, n1);

        // bundle rep from items
        spmm_csr_kernel<<<(NBv + 3) / 4, 256, 0, stream>>>(
            rp3, cs3, vs3, b0 + (size_t)NUv * DD, b0 + (size_t)NUv * DD, NIv + 1, ILbB, NBv);

        // bundle-level propagation
        spmm_csr_kernel<<<(n2 + 3) / 4, 256, 0, stream>>>(
            rp2, cs2, vs2, usersF, bundF, NUv, b1, n2);
        spmm_csr_kernel<<<(n2 + 3) / 4, 256, 0, stream>>>(
            rp2, cs2, vs2, b1, b1, n2, b2, n2);
        finalize_kernel<<<(n2 + 3) / 4, 256, 0, stream>>>(
            usersF, bundF, NUv, b1, b2, b1, n2);
    } else {
        // fallback: atomic COO path
        hipMemsetAsync(b0, 0, (size_t)n1 * DD * sizeof(float), stream);
        spmm_kernel<<<spmmBlocks(E1), 256, 0, stream>>>(
            il_row, il_col, il_val, usersF, itemsF, NUv, b0, E1);
        hipMemsetAsync(b1, 0, (size_t)n1 * DD * sizeof(float), stream);
        spmm_kernel<<<spmmBlocks(E1), 256, 0, stream>>>(
            il_row, il_col, il_val, b0, b0, n1, b1, E1);
        finalize_kernel<<<(n1 + 3) / 4, 256, 0, stream>>>(
            usersF, itemsF, NUv, b0, b1, b0, n1);
        hipMemsetAsync(ILbB, 0, (size_t)NBv * DD * sizeof(float), stream);
        spmm_kernel<<<spmmBlocks(E3), 256, 0, stream>>>(
            agg_row, agg_col, agg_val,
            b0 + (size_t)NUv * DD, b0 + (size_t)NUv * DD, NIv + 1, ILbB, E3);
        hipMemsetAsync(b1, 0, (size_t)n2 * DD * sizeof(float), stream);
        spmm_kernel<<<spmmBlocks(E2), 256, 0, stream>>>(
            bl_row, bl_col, bl_val, usersF, bundF, NUv, b1, E2);
        hipMemsetAsync(b2, 0, (size_t)n2 * DD * sizeof(float), stream);
        spmm_kernel<<<spmmBlocks(E2), 256, 0, stream>>>(
            bl_row, bl_col, bl_val, b1, b1, n2, b2, E2);
        finalize_kernel<<<(n2 + 3) / 4, 256, 0, stream>>>(
            usersF, bundF, NUv, b1, b2, b1, n2);
    }

    // batch: BPR + normalized gathers
    batch_kernel<<<(batch + 3) / 4, 256, 0, stream>>>(
        users, bundles, b0, ILbB, b1, NUv,
        pos1, aug1, pos2, aug2, sums, batch);

    // contrastive loss: tiled sum-of-exp (bounded scores -> no max pass)
    const int yChunks = 8;
    int jChunk = ((batch + yChunks * 64 - 1) / (yChunks * 64)) * 64;
    dim3 cg((batch + 63) / 64, yChunks, 2);
    closs_kernel<<<cg, 256, 0, stream>>>(pos1, aug1, pos2, aug2, S, Dg, batch, jChunk);
    closs_finish<<<2, 256, 0, stream>>>(S, Dg, sums, batch);

    final_kernel<<<1, 1, 0, stream>>>(sums, (float*)d_out, 1.0f / (float)batch);
}

// Round 3
// 932.069 us; speedup vs baseline: 2.4328x; 1.1627x over previous
//
#include <hip/hip_runtime.h>
#include <math.h>

#define DD 64
#define INV_TEMP 4.0f   // 1 / C_TEMP, C_TEMP = 0.25

__device__ __forceinline__ float waveSum(float x) {
#pragma unroll
    for (int off = 32; off > 0; off >>= 1) x += __shfl_xor(x, off, 64);
    return x;
}

// ------------------------- CSR build -------------------------

__global__ void hist_kernel(const int* __restrict__ row, int* __restrict__ cnt, int nE) {
    int i = blockIdx.x * blockDim.x + threadIdx.x;
    int stride = gridDim.x * blockDim.x;
    for (; i < nE; i += stride) atomicAdd(&cnt[row[i]], 1);
}

// 1024-element chunks, 256 threads x 4. In-place safe.
__global__ void scan_chunk(const int* __restrict__ in, int* __restrict__ out,
                           int* __restrict__ blockSums, int n) {
    __shared__ int wtot[4];
    int b = blockIdx.x, t = threadIdx.x;
    int base = b * 1024 + t * 4;
    int v[4];
#pragma unroll
    for (int q = 0; q < 4; q++) v[q] = (base + q < n) ? in[base + q] : 0;
    int s = v[0] + v[1] + v[2] + v[3];
    int lane = t & 63, w = t >> 6;
    int sc = s;
    for (int off = 1; off < 64; off <<= 1) {
        int u = __shfl_up(sc, off, 64);
        if (lane >= off) sc += u;
    }
    if (lane == 63) wtot[w] = sc;
    __syncthreads();
    int woff = 0;
    for (int i = 0; i < w; i++) woff += wtot[i];
    int run = woff + sc - s;
#pragma unroll
    for (int q = 0; q < 4; q++) {
        if (base + q < n) out[base + q] = run;
        run += v[q];
    }
    if (t == 255) blockSums[b] = woff + sc;
}

__global__ void scan_small(int* __restrict__ bs, int nb) {
    __shared__ int wtot[4];
    int t = threadIdx.x;
    int v = (t < nb) ? bs[t] : 0;
    int lane = t & 63, w = t >> 6;
    int sc = v;
    for (int off = 1; off < 64; off <<= 1) {
        int u = __shfl_up(sc, off, 64);
        if (lane >= off) sc += u;
    }
    if (lane == 63) wtot[w] = sc;
    __syncthreads();
    int woff = 0;
    for (int i = 0; i < w; i++) woff += wtot[i];
    if (t < nb) bs[t] = woff + sc - v;
}

__global__ void scan_add(int* __restrict__ out, const int* __restrict__ bs, int n) {
    int off = bs[blockIdx.x];
    int base = blockIdx.x * 1024 + threadIdx.x;
#pragma unroll
    for (int q = 0; q < 4; q++) {
        int i = base + q * 256;
        if (i < n) out[i] += off;
    }
}

// rp: exclusive row starts used as cursors. After this, rp[r] == start(r+1).
__global__ void scatter_kernel(const int* __restrict__ row, const int* __restrict__ col,
                               const float* __restrict__ val,
                               int* __restrict__ rp, int* __restrict__ cs,
                               float* __restrict__ vs, int nE) {
    int i = blockIdx.x * blockDim.x + threadIdx.x;
    int stride = gridDim.x * blockDim.x;
    for (; i < nE; i += stride) {
        int p = atomicAdd(&rp[row[i]], 1);
        cs[p] = col[i];
        vs[p] = val[i];
    }
}

// ------------------------- SpMM -------------------------

// CSR, wave per row, 4 edges per step via float4 gathers (1KB/instr), no atomics.
// Lane group g=lane>>4 owns edge e+g; lane loads 16B chunk sub=lane&15 of the row.
__global__ void spmm_csr4_kernel(
    const int* __restrict__ rp, const int* __restrict__ cs, const float* __restrict__ vs,
    const float* __restrict__ fa, const float* __restrict__ fb, int split,
    float* __restrict__ out, int n)
{
    int lane = threadIdx.x & 63;
    int grp  = lane >> 4;
    int sub  = lane & 15;
    int wave = (blockIdx.x * blockDim.x + threadIdx.x) >> 6;
    int nW   = (gridDim.x * blockDim.x) >> 6;
    for (int r = wave; r < n; r += nW) {
        int start = (r == 0) ? 0 : rp[r - 1];
        int end   = rp[r];
        float4 acc = make_float4(0.f, 0.f, 0.f, 0.f);
        for (int e = start; e < end; e += 8) {
            int e0 = e + grp, e1 = e + 4 + grp;
            bool p0 = e0 < end, p1 = e1 < end;
            int   c0 = p0 ? cs[e0] : 0;
            float v0 = p0 ? vs[e0] : 0.f;
            int   c1 = p1 ? cs[e1] : 0;
            float v1 = p1 ? vs[e1] : 0.f;
            const float* s0 = (c0 < split) ? fa + (size_t)c0 * DD
                                           : fb + (size_t)(c0 - split) * DD;
            const float* s1 = (c1 < split) ? fa + (size_t)c1 * DD
                                           : fb + (size_t)(c1 - split) * DD;
            float4 f0 = *(const float4*)(s0 + sub * 4);
            float4 f1 = *(const float4*)(s1 + sub * 4);
            acc.x += v0 * f0.x; acc.y += v0 * f0.y;
            acc.z += v0 * f0.z; acc.w += v0 * f0.w;
            acc.x += v1 * f1.x; acc.y += v1 * f1.y;
            acc.z += v1 * f1.z; acc.w += v1 * f1.w;
        }
        // fold the 4 edge-group partials
        acc.x += __shfl_xor(acc.x, 16, 64); acc.y += __shfl_xor(acc.y, 16, 64);
        acc.z += __shfl_xor(acc.z, 16, 64); acc.w += __shfl_xor(acc.w, 16, 64);
        acc.x += __shfl_xor(acc.x, 32, 64); acc.y += __shfl_xor(acc.y, 32, 64);
        acc.z += __shfl_xor(acc.z, 32, 64); acc.w += __shfl_xor(acc.w, 32, 64);
        if (lane < 16) *(float4*)(out + (size_t)r * DD + sub * 4) = acc;
    }
}

// Fallback: COO + atomics, used only if ws too small for CSR.
__global__ void spmm_kernel(
    const int* __restrict__ row, const int* __restrict__ col,
    const float* __restrict__ val,
    const float* __restrict__ fa, const float* __restrict__ fb, int split,
    float* __restrict__ out, int nE)
{
    int lane = threadIdx.x & 63;
    int wave = (blockIdx.x * blockDim.x + threadIdx.x) >> 6;
    int nW   = (gridDim.x * blockDim.x) >> 6;
    for (int e = wave; e < nE; e += nW) {
        int r = row[e];
        int c = col[e];
        float v = val[e];
        const float* src = (c < split) ? (fa + (size_t)c * DD)
                                       : (fb + (size_t)(c - split) * DD);
        atomicAdd(out + (size_t)r * DD + lane, v * src[lane]);
    }
}

// acc[r] = f0[r] + g[r]/max(||g||,eps) + h[r]/max(||h||,eps); acc may alias g.
__global__ void finalize_kernel(
    const float* __restrict__ fa, const float* __restrict__ fb, int split,
    const float* __restrict__ g, const float* __restrict__ h,
    float* __restrict__ acc, int n)
{
    int lane = threadIdx.x & 63;
    int wave = (blockIdx.x * blockDim.x + threadIdx.x) >> 6;
    int nW   = (gridDim.x * blockDim.x) >> 6;
    for (int r = wave; r < n; r += nW) {
        float f0 = (r < split) ? fa[(size_t)r * DD + lane]
                               : fb[(size_t)(r - split) * DD + lane];
        float gv = g[(size_t)r * DD + lane];
        float hv = h[(size_t)r * DD + lane];
        float ng = sqrtf(waveSum(gv * gv));
        float nh = sqrtf(waveSum(hv * hv));
        acc[(size_t)r * DD + lane] = f0 + gv / fmaxf(ng, 1e-12f)
                                        + hv / fmaxf(nh, 1e-12f);
    }
}

// ------------------------- batch + losses -------------------------

__global__ void batch_kernel(
    const int* __restrict__ users, const int* __restrict__ bundles,
    const float* __restrict__ IL, const float* __restrict__ ILb,
    const float* __restrict__ BL, int NUv,
    float* __restrict__ pos1, float* __restrict__ aug1,
    float* __restrict__ pos2, float* __restrict__ aug2,
    float* __restrict__ sums, int batch)
{
    int lane = threadIdx.x & 63;
    int wave = (blockIdx.x * blockDim.x + threadIdx.x) >> 6;
    int nW   = (gridDim.x * blockDim.x) >> 6;
    for (int b = wave; b < batch; b += nW) {
        int u   = users[b];
        int bp  = bundles[2 * b];
        int bn  = bundles[2 * b + 1];
        float ilu  = IL [(size_t)u * DD + lane];
        float blu  = BL [(size_t)u * DD + lane];
        float ilb0 = ILb[(size_t)bp * DD + lane];
        float ilb1 = ILb[(size_t)bn * DD + lane];
        float blb0 = BL [(size_t)(NUv + bp) * DD + lane];
        float blb1 = BL [(size_t)(NUv + bn) * DD + lane];
        float d0 = waveSum(ilu * ilb0 + blu * blb0);
        float d1 = waveSum(ilu * ilb1 + blu * blb1);
        float x  = d1 - d0;
        float sp = fmaxf(x, 0.f) + log1pf(expf(-fabsf(x)));
        if (lane == 0) atomicAdd(&sums[0], sp);
        float nilu = sqrtf(waveSum(ilu * ilu));
        float nblu = sqrtf(waveSum(blu * blu));
        float nilb = sqrtf(waveSum(ilb0 * ilb0));
        float nblb = sqrtf(waveSum(blb0 * blb0));
        pos1[(size_t)b * DD + lane] = ilu  / fmaxf(nilu, 1e-12f);
        aug1[(size_t)b * DD + lane] = blu  / fmaxf(nblu, 1e-12f);
        pos2[(size_t)b * DD + lane] = ilb0 / fmaxf(nilb, 1e-12f);
        aug2[(size_t)b * DD + lane] = blb0 / fmaxf(nblb, 1e-12f);
    }
}

__device__ __forceinline__ void load_tile_T(const float* __restrict__ src, int rowBase,
                                            int batch, float* __restrict__ dst, int tx) {
    int i = tx >> 2, c = tx & 3;
#pragma unroll
    for (int t = 0; t < 4; t++) {
        int k0 = c * 4 + t * 16;
        float4 v = make_float4(0.f, 0.f, 0.f, 0.f);
        int gi = rowBase + i;
        if (gi < batch) v = *(const float4*)&src[(size_t)gi * DD + k0];
        dst[(k0 + 0) * 68 + i] = v.x;
        dst[(k0 + 1) * 68 + i] = v.y;
        dst[(k0 + 2) * 68 + i] = v.z;
        dst[(k0 + 3) * 68 + i] = v.w;
    }
}

// Scores bounded (unit-norm rows, temp=0.25 -> t in [-4,4]) -> plain sum-of-exp.
__global__ void closs_kernel(
    const float* __restrict__ pos1, const float* __restrict__ aug1,
    const float* __restrict__ pos2, const float* __restrict__ aug2,
    float* __restrict__ S, float* __restrict__ Dg, int batch, int jChunk)
{
    const float* pos = blockIdx.z ? pos2 : pos1;
    const float* aug = blockIdx.z ? aug2 : aug1;
    __shared__ float Pt[64 * 68];
    __shared__ float At[64 * 68];
    __shared__ float red[64 * 17];
    int tx = threadIdx.x;
    int iBase = blockIdx.x * 64;
    int jBeg = blockIdx.y * jChunk;
    int jEnd = min(jBeg + jChunk, batch);
    load_tile_T(pos, iBase, batch, Pt, tx);
    int tr = tx >> 4, tc = tx & 15;
    float rs[4] = {0.f, 0.f, 0.f, 0.f};
    for (int j0 = jBeg; j0 < jEnd; j0 += 64) {
        __syncthreads();
        load_tile_T(aug, j0, batch, At, tx);
        __syncthreads();
        float acc[16];
#pragma unroll
        for (int q = 0; q < 16; q++) acc[q] = 0.f;
#pragma unroll 8
        for (int k = 0; k < 64; k++) {
            float4 pv = *(const float4*)&Pt[k * 68 + 4 * tr];
            float4 av = *(const float4*)&At[k * 68 + 4 * tc];
            acc[0]  += pv.x * av.x;  acc[1]  += pv.x * av.y;
            acc[2]  += pv.x * av.z;  acc[3]  += pv.x * av.w;
            acc[4]  += pv.y * av.x;  acc[5]  += pv.y * av.y;
            acc[6]  += pv.y * av.z;  acc[7]  += pv.y * av.w;
            acc[8]  += pv.z * av.x;  acc[9]  += pv.z * av.y;
            acc[10] += pv.z * av.z;  acc[11] += pv.z * av.w;
            acc[12] += pv.w * av.x;  acc[13] += pv.w * av.y;
            acc[14] += pv.w * av.z;  acc[15] += pv.w * av.w;
        }
#pragma unroll
        for (int qi = 0; qi < 4; qi++) {
            int gi = iBase + 4 * tr + qi;
#pragma unroll
            for (int qj = 0; qj < 4; qj++) {
                int gj = j0 + 4 * tc + qj;
                float t = acc[qi * 4 + qj] * INV_TEMP;
                if (gi < batch && gj < batch) {
                    rs[qi] += __expf(t);
                    if (gi == gj) Dg[blockIdx.z * batch + gi] = t;
                }
            }
        }
    }
    __syncthreads();
#pragma unroll
    for (int qi = 0; qi < 4; qi++) red[(4 * tr + qi) * 17 + tc] = rs[qi];
    __syncthreads();
    if (tx < 64) {
        float s = 0.f;
#pragma unroll
        for (int c = 0; c < 16; c++) s += red[tx * 17 + c];
        int gi = iBase + tx;
        if (gi < batch) atomicAdd(&S[blockIdx.z * batch + gi], s);
    }
}

__global__ void closs_finish(const float* __restrict__ S, const float* __restrict__ Dg,
                             float* __restrict__ sums, int batch)
{
    int m = blockIdx.x;
    int tid = threadIdx.x;
    float local = 0.f;
    for (int i = tid; i < batch; i += blockDim.x)
        local += logf(S[m * batch + i]) - Dg[m * batch + i];
    local = waveSum(local);
    __shared__ float wsm[4];
    if ((tid & 63) == 0) wsm[tid >> 6] = local;
    __syncthreads();
    if (tid == 0) sums[1 + m] = wsm[0] + wsm[1] + wsm[2] + wsm[3];
}

__global__ void final_kernel(const float* __restrict__ sums,
                             float* __restrict__ out, float invB)
{
    if (threadIdx.x == 0 && blockIdx.x == 0) {
        out[0] = sums[0] * invB;
        out[1] = 0.5f * (sums[1] + sums[2]) * invB;
    }
}

// ------------------------- driver -------------------------

static inline void build_csr(const int* row, const int* col, const float* val,
                             int* rp, int* cs, float* vs, int* bsum,
                             int n, int E, hipStream_t stream)
{
    hipMemsetAsync(rp, 0, (size_t)n * sizeof(int), stream);
    int hb = (E + 255) / 256; if (hb > 8192) hb = 8192;
    hist_kernel<<<hb, 256, 0, stream>>>(row, rp, E);
    int nb = (n + 1023) / 1024;
    scan_chunk<<<nb, 256, 0, stream>>>(rp, rp, bsum, n);
    scan_small<<<1, 256, 0, stream>>>(bsum, nb);
    scan_add<<<nb, 256, 0, stream>>>(rp, bsum, n);
    scatter_kernel<<<hb, 256, 0, stream>>>(row, col, val, rp, cs, vs, E);
}

extern "C" void kernel_launch(void* const* d_in, const int* in_sizes, int n_in,
                              void* d_out, int out_size, void* d_ws, size_t ws_size,
                              hipStream_t stream)
{
    const float* usersF = (const float*)d_in[0];
    const float* itemsF = (const float*)d_in[1];
    const float* bundF  = (const float*)d_in[2];
    const int*   il_row = (const int*)d_in[3];
    const int*   il_col = (const int*)d_in[4];
    const float* il_val = (const float*)d_in[5];
    const int*   bl_row = (const int*)d_in[6];
    const int*   bl_col = (const int*)d_in[7];
    const float* bl_val = (const float*)d_in[8];
    const int*   agg_row = (const int*)d_in[9];
    const int*   agg_col = (const int*)d_in[10];
    const float* agg_val = (const float*)d_in[11];
    const int*   users   = (const int*)d_in[12];
    const int*   bundles = (const int*)d_in[13];

    const int NUv = in_sizes[0] / DD;
    const int NIv = in_sizes[1] / DD;
    const int NBv = in_sizes[2] / DD;
    const int E1 = in_sizes[3], E2 = in_sizes[6], E3 = in_sizes[9];
    const int batch = in_sizes[12];
    const int n1 = NUv + NIv;
    const int n2 = NUv + NBv;

    float* ws = (float*)d_ws;
    size_t off = 0;
    float* sums = ws + off;      off += 16;
    float* S    = ws + off;      off += (size_t)2 * batch;
    float* Dg   = ws + off;      off += (size_t)2 * batch;
    float* b0   = ws + off;      off += (size_t)n1 * DD;
    float* b1   = ws + off;      off += (size_t)n1 * DD;
    float* b2   = ws + off;      off += (size_t)n2 * DD;
    float* ILbB = ws + off;      off += (size_t)NBv * DD;
    float* pos1 = ws + off;      off += (size_t)batch * DD;
    float* aug1 = ws + off;      off += (size_t)batch * DD;
    float* pos2 = ws + off;      off += (size_t)batch * DD;
    float* aug2 = ws + off;      off += (size_t)batch * DD;
    int*   bsum = (int*)(ws + off);   off += 256;
    int*   rp1  = (int*)(ws + off);   off += (size_t)n1;
    int*   cs1  = (int*)(ws + off);   off += (size_t)E1;
    float* vs1  = ws + off;           off += (size_t)E1;
    int*   rp2  = (int*)(ws + off);   off += (size_t)n2;
    int*   cs2  = (int*)(ws + off);   off += (size_t)E2;
    float* vs2  = ws + off;           off += (size_t)E2;
    int*   rp3  = (int*)(ws + off);   off += (size_t)NBv;
    int*   cs3  = (int*)(ws + off);   off += (size_t)E3;
    float* vs3  = ws + off;           off += (size_t)E3;
    const bool useCSR = (off * sizeof(float) <= ws_size);

    hipMemsetAsync(sums, 0, 16 * sizeof(float), stream);
    hipMemsetAsync(S, 0, (size_t)2 * batch * sizeof(float), stream);

    auto spmmBlocks = [](int E) { int w = (E + 3) / 4; return w > 16384 ? 16384 : w; };

    if (useCSR) {
        build_csr(il_row, il_col, il_val, rp1, cs1, vs1, bsum, n1, E1, stream);
        build_csr(bl_row, bl_col, bl_val, rp2, cs2, vs2, bsum, n2, E2, stream);
        build_csr(agg_row, agg_col, agg_val, rp3, cs3, vs3, bsum, NBv, E3, stream);

        spmm_csr4_kernel<<<(n1 + 3) / 4, 256, 0, stream>>>(
            rp1, cs1, vs1, usersF, itemsF, NUv, b0, n1);
        spmm_csr4_kernel<<<(n1 + 3) / 4, 256, 0, stream>>>(
            rp1, cs1, vs1, b0, b0, n1, b1, n1);
        finalize_kernel<<<(n1 + 3) / 4, 256, 0, stream>>>(
            usersF, itemsF, NUv, b0, b1, b0, n1);

        spmm_csr4_kernel<<<(NBv + 3) / 4, 256, 0, stream>>>(
            rp3, cs3, vs3, b0 + (size_t)NUv * DD, b0 + (size_t)NUv * DD, NIv + 1, ILbB, NBv);

        spmm_csr4_kernel<<<(n2 + 3) / 4, 256, 0, stream>>>(
            rp2, cs2, vs2, usersF, bundF, NUv, b1, n2);
        spmm_csr4_kernel<<<(n2 + 3) / 4, 256, 0, stream>>>(
            rp2, cs2, vs2, b1, b1, n2, b2, n2);
        finalize_kernel<<<(n2 + 3) / 4, 256, 0, stream>>>(
            usersF, bundF, NUv, b1, b2, b1, n2);
    } else {
        hipMemsetAsync(b0, 0, (size_t)n1 * DD * sizeof(float), stream);
        spmm_kernel<<<spmmBlocks(E1), 256, 0, stream>>>(
            il_row, il_col, il_val, usersF, itemsF, NUv, b0, E1);
        hipMemsetAsync(b1, 0, (size_t)n1 * DD * sizeof(float), stream);
        spmm_kernel<<<spmmBlocks(E1), 256, 0, stream>>>(
            il_row, il_col, il_val, b0, b0, n1, b1, E1);
        finalize_kernel<<<(n1 + 3) / 4, 256, 0, stream>>>(
            usersF, itemsF, NUv, b0, b1, b0, n1);
        hipMemsetAsync(ILbB, 0, (size_t)NBv * DD * sizeof(float), stream);
        spmm_kernel<<<spmmBlocks(E3), 256, 0, stream>>>(
            agg_row, agg_col, agg_val,
            b0 + (size_t)NUv * DD, b0 + (size_t)NUv * DD, NIv + 1, ILbB, E3);
        hipMemsetAsync(b1, 0, (size_t)n2 * DD * sizeof(float), stream);
        spmm_kernel<<<spmmBlocks(E2), 256, 0, stream>>>(
            bl_row, bl_col, bl_val, usersF, bundF, NUv, b1, E2);
        hipMemsetAsync(b2, 0, (size_t)n2 * DD * sizeof(float), stream);
        spmm_kernel<<<spmmBlocks(E2), 256, 0, stream>>>(
            bl_row, bl_col, bl_val, b1, b1, n2, b2, E2);
        finalize_kernel<<<(n2 + 3) / 4, 256, 0, stream>>>(
            usersF, bundF, NUv, b1, b2, b1, n2);
    }

    batch_kernel<<<(batch + 3) / 4, 256, 0, stream>>>(
        users, bundles, b0, ILbB, b1, NUv,
        pos1, aug1, pos2, aug2, sums, batch);

    const int yChunks = 8;
    int jChunk = ((batch + yChunks * 64 - 1) / (yChunks * 64)) * 64;
    dim3 cg((batch + 63) / 64, yChunks, 2);
    closs_kernel<<<cg, 256, 0, stream>>>(pos1, aug1, pos2, aug2, S, Dg, batch, jChunk);
    closs_finish<<<2, 256, 0, stream>>>(S, Dg, sums, batch);

    final_kernel<<<1, 1, 0, stream>>>(sums, (float*)d_out, 1.0f / (float)batch);
}

// Round 4
// 865.060 us; speedup vs baseline: 2.6212x; 1.0775x over previous
//
#include <hip/hip_runtime.h>
#include <math.h>

#define DD 64
#define INV_TEMP 4.0f   // 1 / C_TEMP, C_TEMP = 0.25

__device__ __forceinline__ float waveSum(float x) {
#pragma unroll
    for (int off = 32; off > 0; off >>= 1) x += __shfl_xor(x, off, 64);
    return x;
}

// ------------------------- fused CSR build -------------------------
// Global row space: [0,n1) graph1, [n1,n1+n2) graph2, [n1+n2,n1+n2+nb3) graph3.
// pv_all positions are global across the concatenated edge lists.

__global__ void hist3_kernel(
    const int* __restrict__ r1, const int* __restrict__ r2, const int* __restrict__ r3,
    int E1, int E2, int E3, int b2, int b3, int* __restrict__ cnt)
{
    int i = blockIdx.x * blockDim.x + threadIdx.x;
    int stride = gridDim.x * blockDim.x;
    int Et = E1 + E2 + E3;
    for (; i < Et; i += stride) {
        int idx;
        if (i < E1)            idx = __builtin_nontemporal_load(&r1[i]);
        else if (i < E1 + E2)  idx = b2 + __builtin_nontemporal_load(&r2[i - E1]);
        else                   idx = b3 + __builtin_nontemporal_load(&r3[i - E1 - E2]);
        atomicAdd(&cnt[idx], 1);
    }
}

// 2048-element chunks, 256 threads x 8. In-place safe.
__global__ void scan_chunk8(int* __restrict__ data, int* __restrict__ blockSums, int n) {
    __shared__ int wtot[4];
    int b = blockIdx.x, t = threadIdx.x;
    int base = b * 2048 + t * 8;
    int v[8];
    int s = 0;
#pragma unroll
    for (int q = 0; q < 8; q++) {
        v[q] = (base + q < n) ? data[base + q] : 0;
        s += v[q];
    }
    int lane = t & 63, w = t >> 6;
    int sc = s;
    for (int off = 1; off < 64; off <<= 1) {
        int u = __shfl_up(sc, off, 64);
        if (lane >= off) sc += u;
    }
    if (lane == 63) wtot[w] = sc;
    __syncthreads();
    int woff = 0;
    for (int i = 0; i < w; i++) woff += wtot[i];
    int run = woff + sc - s;   // exclusive prefix for this thread's first elem
#pragma unroll
    for (int q = 0; q < 8; q++) {
        if (base + q < n) data[base + q] = run;
        run += v[q];
    }
    if (t == 255) blockSums[b] = woff + sc;
}

// single block, nb <= 256
__global__ void scan_small(int* __restrict__ bs, int nb) {
    __shared__ int wtot[4];
    int t = threadIdx.x;
    int v = (t < nb) ? bs[t] : 0;
    int lane = t & 63, w = t >> 6;
    int sc = v;
    for (int off = 1; off < 64; off <<= 1) {
        int u = __shfl_up(sc, off, 64);
        if (lane >= off) sc += u;
    }
    if (lane == 63) wtot[w] = sc;
    __syncthreads();
    int woff = 0;
    for (int i = 0; i < w; i++) woff += wtot[i];
    if (t < nb) bs[t] = woff + sc - v;
}

__global__ void scan_add8(int* __restrict__ data, const int* __restrict__ bs, int n) {
    int off = bs[blockIdx.x];
    int base = blockIdx.x * 2048 + threadIdx.x;
#pragma unroll
    for (int q = 0; q < 8; q++) {
        int i = base + q * 256;
        if (i < n) data[i] += off;
    }
}

// rp: exclusive row starts used as cursors. After this, rp[idx] == start(idx+1).
// One packed 8B store per edge (col, val-bits).
__global__ void scatter3_kernel(
    const int* __restrict__ r1, const int* __restrict__ c1, const float* __restrict__ v1,
    const int* __restrict__ r2, const int* __restrict__ c2, const float* __restrict__ v2,
    const int* __restrict__ r3, const int* __restrict__ c3, const float* __restrict__ v3,
    int E1, int E2, int E3, int b2, int b3,
    int* __restrict__ rp, int2* __restrict__ pv)
{
    int i = blockIdx.x * blockDim.x + threadIdx.x;
    int stride = gridDim.x * blockDim.x;
    int Et = E1 + E2 + E3;
    for (; i < Et; i += stride) {
        int row, colv; float val;
        if (i < E1) {
            row = __builtin_nontemporal_load(&r1[i]);
            colv = __builtin_nontemporal_load(&c1[i]);
            val = __builtin_nontemporal_load(&v1[i]);
        } else if (i < E1 + E2) {
            int j = i - E1;
            row = b2 + __builtin_nontemporal_load(&r2[j]);
            colv = __builtin_nontemporal_load(&c2[j]);
            val = __builtin_nontemporal_load(&v2[j]);
        } else {
            int j = i - E1 - E2;
            row = b3 + __builtin_nontemporal_load(&r3[j]);
            colv = __builtin_nontemporal_load(&c3[j]);
            val = __builtin_nontemporal_load(&v3[j]);
        }
        int p = atomicAdd(&rp[row], 1);
        pv[p] = make_int2(colv, __float_as_int(val));
    }
}

// ------------------------- SpMM -------------------------

// CSR (global row space), wave per row, 4 edges per step via float4 gathers.
// Lane group g=lane>>4 owns edge e+g; lane loads 16B chunk sub=lane&15.
__global__ void spmm_csr4_kernel(
    const int* __restrict__ rp, const int2* __restrict__ pv, int rbase,
    const float* __restrict__ fa, const float* __restrict__ fb, int split,
    float* __restrict__ out, int n)
{
    int lane = threadIdx.x & 63;
    int grp  = lane >> 4;
    int sub  = lane & 15;
    int wave = (blockIdx.x * blockDim.x + threadIdx.x) >> 6;
    int nW   = (gridDim.x * blockDim.x) >> 6;
    for (int r = wave; r < n; r += nW) {
        int idx = rbase + r;
        int start = (idx == 0) ? 0 : rp[idx - 1];
        int end   = rp[idx];
        float4 acc = make_float4(0.f, 0.f, 0.f, 0.f);
        for (int e = start; e < end; e += 8) {
            int e0 = e + grp, e1 = e + 4 + grp;
            bool p0 = e0 < end, p1 = e1 < end;
            int2 m0 = p0 ? pv[e0] : make_int2(0, 0);
            int2 m1 = p1 ? pv[e1] : make_int2(0, 0);
            int   c0 = m0.x;  float v0 = __int_as_float(m0.y);
            int   c1 = m1.x;  float v1 = __int_as_float(m1.y);
            const float* s0 = (c0 < split) ? fa + (size_t)c0 * DD
                                           : fb + (size_t)(c0 - split) * DD;
            const float* s1 = (c1 < split) ? fa + (size_t)c1 * DD
                                           : fb + (size_t)(c1 - split) * DD;
            float4 f0 = *(const float4*)(s0 + sub * 4);
            float4 f1 = *(const float4*)(s1 + sub * 4);
            acc.x += v0 * f0.x; acc.y += v0 * f0.y;
            acc.z += v0 * f0.z; acc.w += v0 * f0.w;
            acc.x += v1 * f1.x; acc.y += v1 * f1.y;
            acc.z += v1 * f1.z; acc.w += v1 * f1.w;
        }
        acc.x += __shfl_xor(acc.x, 16, 64); acc.y += __shfl_xor(acc.y, 16, 64);
        acc.z += __shfl_xor(acc.z, 16, 64); acc.w += __shfl_xor(acc.w, 16, 64);
        acc.x += __shfl_xor(acc.x, 32, 64); acc.y += __shfl_xor(acc.y, 32, 64);
        acc.z += __shfl_xor(acc.z, 32, 64); acc.w += __shfl_xor(acc.w, 32, 64);
        if (lane < 16) *(float4*)(out + (size_t)r * DD + sub * 4) = acc;
    }
}

// Fallback: COO + atomics, used only if ws too small for CSR.
__global__ void spmm_kernel(
    const int* __restrict__ row, const int* __restrict__ col,
    const float* __restrict__ val,
    const float* __restrict__ fa, const float* __restrict__ fb, int split,
    float* __restrict__ out, int nE)
{
    int lane = threadIdx.x & 63;
    int wave = (blockIdx.x * blockDim.x + threadIdx.x) >> 6;
    int nW   = (gridDim.x * blockDim.x) >> 6;
    for (int e = wave; e < nE; e += nW) {
        int r = row[e];
        int c = col[e];
        float v = val[e];
        const float* src = (c < split) ? (fa + (size_t)c * DD)
                                       : (fb + (size_t)(c - split) * DD);
        atomicAdd(out + (size_t)r * DD + lane, v * src[lane]);
    }
}

// acc[r] = f0[r] + g[r]/max(||g||,eps) + h[r]/max(||h||,eps); acc may alias g.
__global__ void finalize_kernel(
    const float* __restrict__ fa, const float* __restrict__ fb, int split,
    const float* __restrict__ g, const float* __restrict__ h,
    float* __restrict__ acc, int n)
{
    int lane = threadIdx.x & 63;
    int wave = (blockIdx.x * blockDim.x + threadIdx.x) >> 6;
    int nW   = (gridDim.x * blockDim.x) >> 6;
    for (int r = wave; r < n; r += nW) {
        float f0 = (r < split) ? fa[(size_t)r * DD + lane]
                               : fb[(size_t)(r - split) * DD + lane];
        float gv = g[(size_t)r * DD + lane];
        float hv = h[(size_t)r * DD + lane];
        float ng = sqrtf(waveSum(gv * gv));
        float nh = sqrtf(waveSum(hv * hv));
        acc[(size_t)r * DD + lane] = f0 + gv / fmaxf(ng, 1e-12f)
                                        + hv / fmaxf(nh, 1e-12f);
    }
}

// ------------------------- batch + losses -------------------------

__global__ void batch_kernel(
    const int* __restrict__ users, const int* __restrict__ bundles,
    const float* __restrict__ IL, const float* __restrict__ ILb,
    const float* __restrict__ BL, int NUv,
    float* __restrict__ pos1, float* __restrict__ aug1,
    float* __restrict__ pos2, float* __restrict__ aug2,
    float* __restrict__ sums, int batch)
{
    int lane = threadIdx.x & 63;
    int wave = (blockIdx.x * blockDim.x + threadIdx.x) >> 6;
    int nW   = (gridDim.x * blockDim.x) >> 6;
    for (int b = wave; b < batch; b += nW) {
        int u   = users[b];
        int bp  = bundles[2 * b];
        int bn  = bundles[2 * b + 1];
        float ilu  = IL [(size_t)u * DD + lane];
        float blu  = BL [(size_t)u * DD + lane];
        float ilb0 = ILb[(size_t)bp * DD + lane];
        float ilb1 = ILb[(size_t)bn * DD + lane];
        float blb0 = BL [(size_t)(NUv + bp) * DD + lane];
        float blb1 = BL [(size_t)(NUv + bn) * DD + lane];
        float d0 = waveSum(ilu * ilb0 + blu * blb0);
        float d1 = waveSum(ilu * ilb1 + blu * blb1);
        float x  = d1 - d0;
        float sp = fmaxf(x, 0.f) + log1pf(expf(-fabsf(x)));
        if (lane == 0) atomicAdd(&sums[0], sp);
        float nilu = sqrtf(waveSum(ilu * ilu));
        float nblu = sqrtf(waveSum(blu * blu));
        float nilb = sqrtf(waveSum(ilb0 * ilb0));
        float nblb = sqrtf(waveSum(blb0 * blb0));
        pos1[(size_t)b * DD + lane] = ilu  / fmaxf(nilu, 1e-12f);
        aug1[(size_t)b * DD + lane] = blu  / fmaxf(nblu, 1e-12f);
        pos2[(size_t)b * DD + lane] = ilb0 / fmaxf(nilb, 1e-12f);
        aug2[(size_t)b * DD + lane] = blb0 / fmaxf(nblb, 1e-12f);
    }
}

__device__ __forceinline__ void load_tile_T(const float* __restrict__ src, int rowBase,
                                            int batch, float* __restrict__ dst, int tx) {
    int i = tx >> 2, c = tx & 3;
#pragma unroll
    for (int t = 0; t < 4; t++) {
        int k0 = c * 4 + t * 16;
        float4 v = make_float4(0.f, 0.f, 0.f, 0.f);
        int gi = rowBase + i;
        if (gi < batch) v = *(const float4*)&src[(size_t)gi * DD + k0];
        dst[(k0 + 0) * 68 + i] = v.x;
        dst[(k0 + 1) * 68 + i] = v.y;
        dst[(k0 + 2) * 68 + i] = v.z;
        dst[(k0 + 3) * 68 + i] = v.w;
    }
}

// Scores bounded (unit-norm rows, temp=0.25 -> t in [-4,4]) -> plain sum-of-exp.
__global__ void closs_kernel(
    const float* __restrict__ pos1, const float* __restrict__ aug1,
    const float* __restrict__ pos2, const float* __restrict__ aug2,
    float* __restrict__ S, float* __restrict__ Dg, int batch, int jChunk)
{
    const float* pos = blockIdx.z ? pos2 : pos1;
    const float* aug = blockIdx.z ? aug2 : aug1;
    __shared__ float Pt[64 * 68];
    __shared__ float At[64 * 68];
    __shared__ float red[64 * 17];
    int tx = threadIdx.x;
    int iBase = blockIdx.x * 64;
    int jBeg = blockIdx.y * jChunk;
    int jEnd = min(jBeg + jChunk, batch);
    load_tile_T(pos, iBase, batch, Pt, tx);
    int tr = tx >> 4, tc = tx & 15;
    float rs[4] = {0.f, 0.f, 0.f, 0.f};
    for (int j0 = jBeg; j0 < jEnd; j0 += 64) {
        __syncthreads();
        load_tile_T(aug, j0, batch, At, tx);
        __syncthreads();
        float acc[16];
#pragma unroll
        for (int q = 0; q < 16; q++) acc[q] = 0.f;
#pragma unroll 8
        for (int k = 0; k < 64; k++) {
            float4 pv = *(const float4*)&Pt[k * 68 + 4 * tr];
            float4 av = *(const float4*)&At[k * 68 + 4 * tc];
            acc[0]  += pv.x * av.x;  acc[1]  += pv.x * av.y;
            acc[2]  += pv.x * av.z;  acc[3]  += pv.x * av.w;
            acc[4]  += pv.y * av.x;  acc[5]  += pv.y * av.y;
            acc[6]  += pv.y * av.z;  acc[7]  += pv.y * av.w;
            acc[8]  += pv.z * av.x;  acc[9]  += pv.z * av.y;
            acc[10] += pv.z * av.z;  acc[11] += pv.z * av.w;
            acc[12] += pv.w * av.x;  acc[13] += pv.w * av.y;
            acc[14] += pv.w * av.z;  acc[15] += pv.w * av.w;
        }
#pragma unroll
        for (int qi = 0; qi < 4; qi++) {
            int gi = iBase + 4 * tr + qi;
#pragma unroll
            for (int qj = 0; qj < 4; qj++) {
                int gj = j0 + 4 * tc + qj;
                float t = acc[qi * 4 + qj] * INV_TEMP;
                if (gi < batch && gj < batch) {
                    rs[qi] += __expf(t);
                    if (gi == gj) Dg[blockIdx.z * batch + gi] = t;
                }
            }
        }
    }
    __syncthreads();
#pragma unroll
    for (int qi = 0; qi < 4; qi++) red[(4 * tr + qi) * 17 + tc] = rs[qi];
    __syncthreads();
    if (tx < 64) {
        float s = 0.f;
#pragma unroll
        for (int c = 0; c < 16; c++) s += red[tx * 17 + c];
        int gi = iBase + tx;
        if (gi < batch) atomicAdd(&S[blockIdx.z * batch + gi], s);
    }
}

// Single block: finishes both c-loss sums and writes the 2-element output.
__global__ void closs_finish(const float* __restrict__ S, const float* __restrict__ Dg,
                             const float* __restrict__ sums,
                             float* __restrict__ out, int batch, float invB)
{
    int tid = threadIdx.x;
    __shared__ float wsm[2][4];
    float tot[2];
#pragma unroll
    for (int m = 0; m < 2; m++) {
        float local = 0.f;
        for (int i = tid; i < batch; i += blockDim.x)
            local += logf(S[m * batch + i]) - Dg[m * batch + i];
        local = waveSum(local);
        if ((tid & 63) == 0) wsm[m][tid >> 6] = local;
    }
    __syncthreads();
    if (tid == 0) {
#pragma unroll
        for (int m = 0; m < 2; m++)
            tot[m] = wsm[m][0] + wsm[m][1] + wsm[m][2] + wsm[m][3];
        out[0] = sums[0] * invB;
        out[1] = 0.5f * (tot[0] + tot[1]) * invB;
    }
}

// ------------------------- driver -------------------------

extern "C" void kernel_launch(void* const* d_in, const int* in_sizes, int n_in,
                              void* d_out, int out_size, void* d_ws, size_t ws_size,
                              hipStream_t stream)
{
    const float* usersF = (const float*)d_in[0];
    const float* itemsF = (const float*)d_in[1];
    const float* bundF  = (const float*)d_in[2];
    const int*   il_row = (const int*)d_in[3];
    const int*   il_col = (const int*)d_in[4];
    const float* il_val = (const float*)d_in[5];
    const int*   bl_row = (const int*)d_in[6];
    const int*   bl_col = (const int*)d_in[7];
    const float* bl_val = (const float*)d_in[8];
    const int*   agg_row = (const int*)d_in[9];
    const int*   agg_col = (const int*)d_in[10];
    const float* agg_val = (const float*)d_in[11];
    const int*   users   = (const int*)d_in[12];
    const int*   bundles = (const int*)d_in[13];

    const int NUv = in_sizes[0] / DD;
    const int NIv = in_sizes[1] / DD;
    const int NBv = in_sizes[2] / DD;
    const int E1 = in_sizes[3], E2 = in_sizes[6], E3 = in_sizes[9];
    const int batch = in_sizes[12];
    const int n1 = NUv + NIv;
    const int n2 = NUv + NBv;
    const int ntot = n1 + n2 + NBv;
    const int Etot = E1 + E2 + E3;

    float* ws = (float*)d_ws;
    size_t off = 0;
    float* sums = ws + off;      off += 16;
    float* S    = ws + off;      off += (size_t)2 * batch;
    float* Dg   = ws + off;      off += (size_t)2 * batch;
    float* b0   = ws + off;      off += (size_t)n1 * DD;
    float* b1   = ws + off;      off += (size_t)n1 * DD;
    float* b2   = ws + off;      off += (size_t)n2 * DD;
    float* ILbB = ws + off;      off += (size_t)NBv * DD;
    float* pos1 = ws + off;      off += (size_t)batch * DD;
    float* aug1 = ws + off;      off += (size_t)batch * DD;
    float* pos2 = ws + off;      off += (size_t)batch * DD;
    float* aug2 = ws + off;      off += (size_t)batch * DD;
    int*   bsum = (int*)(ws + off);   off += 256;
    int*   rpA  = (int*)(ws + off);   off += (size_t)ntot;
    off = (off + 1) & ~(size_t)1;     // 8B align
    int2*  pvA  = (int2*)(ws + off);  off += (size_t)2 * Etot;
    const bool useCSR = (off * sizeof(float) <= ws_size);

    hipMemsetAsync(sums, 0, 16 * sizeof(float), stream);
    hipMemsetAsync(S, 0, (size_t)2 * batch * sizeof(float), stream);

    auto spmmBlocks = [](int E) { int w = (E + 3) / 4; return w > 16384 ? 16384 : w; };

    if (useCSR) {
        // ---- fused CSR build for all three graphs ----
        hipMemsetAsync(rpA, 0, (size_t)ntot * sizeof(int), stream);
        int hb = (Etot + 255) / 256; if (hb > 8192) hb = 8192;
        hist3_kernel<<<hb, 256, 0, stream>>>(
            il_row, bl_row, agg_row, E1, E2, E3, n1, n1 + n2, rpA);
        int nb = (ntot + 2047) / 2048;
        scan_chunk8<<<nb, 256, 0, stream>>>(rpA, bsum, ntot);
        scan_small<<<1, 256, 0, stream>>>(bsum, nb);
        scan_add8<<<nb, 256, 0, stream>>>(rpA, bsum, ntot);
        scatter3_kernel<<<hb, 256, 0, stream>>>(
            il_row, il_col, il_val, bl_row, bl_col, bl_val,
            agg_row, agg_col, agg_val, E1, E2, E3, n1, n1 + n2, rpA, pvA);

        // ---- item-level propagation ----
        spmm_csr4_kernel<<<(n1 + 3) / 4, 256, 0, stream>>>(
            rpA, pvA, 0, usersF, itemsF, NUv, b0, n1);
        spmm_csr4_kernel<<<(n1 + 3) / 4, 256, 0, stream>>>(
            rpA, pvA, 0, b0, b0, n1, b1, n1);
        finalize_kernel<<<(n1 + 3) / 4, 256, 0, stream>>>(
            usersF, itemsF, NUv, b0, b1, b0, n1);

        // ---- bundle rep from items ----
        spmm_csr4_kernel<<<(NBv + 3) / 4, 256, 0, stream>>>(
            rpA, pvA, n1 + n2, b0 + (size_t)NUv * DD, b0 + (size_t)NUv * DD,
            NIv + 1, ILbB, NBv);

        // ---- bundle-level propagation ----
        spmm_csr4_kernel<<<(n2 + 3) / 4, 256, 0, stream>>>(
            rpA, pvA, n1, usersF, bundF, NUv, b1, n2);
        spmm_csr4_kernel<<<(n2 + 3) / 4, 256, 0, stream>>>(
            rpA, pvA, n1, b1, b1, n2, b2, n2);
        finalize_kernel<<<(n2 + 3) / 4, 256, 0, stream>>>(
            usersF, bundF, NUv, b1, b2, b1, n2);
    } else {
        hipMemsetAsync(b0, 0, (size_t)n1 * DD * sizeof(float), stream);
        spmm_kernel<<<spmmBlocks(E1), 256, 0, stream>>>(
            il_row, il_col, il_val, usersF, itemsF, NUv, b0, E1);
        hipMemsetAsync(b1, 0, (size_t)n1 * DD * sizeof(float), stream);
        spmm_kernel<<<spmmBlocks(E1), 256, 0, stream>>>(
            il_row, il_col, il_val, b0, b0, n1, b1, E1);
        finalize_kernel<<<(n1 + 3) / 4, 256, 0, stream>>>(
            usersF, itemsF, NUv, b0, b1, b0, n1);
        hipMemsetAsync(ILbB, 0, (size_t)NBv * DD * sizeof(float), stream);
        spmm_kernel<<<spmmBlocks(E3), 256, 0, stream>>>(
            agg_row, agg_col, agg_val,
            b0 + (size_t)NUv * DD, b0 + (size_t)NUv * DD, NIv + 1, ILbB, E3);
        hipMemsetAsync(b1, 0, (size_t)n2 * DD * sizeof(float), stream);
        spmm_kernel<<<spmmBlocks(E2), 256, 0, stream>>>(
            bl_row, bl_col, bl_val, usersF, bundF, NUv, b1, E2);
        hipMemsetAsync(b2, 0, (size_t)n2 * DD * sizeof(float), stream);
        spmm_kernel<<<spmmBlocks(E2), 256, 0, stream>>>(
            bl_row, bl_col, bl_val, b1, b1, n2, b2, E2);
        finalize_kernel<<<(n2 + 3) / 4, 256, 0, stream>>>(
            usersF, bundF, NUv, b1, b2, b1, n2);
    }

    batch_kernel<<<(batch + 3) / 4, 256, 0, stream>>>(
        users, bundles, b0, ILbB, b1, NUv,
        pos1, aug1, pos2, aug2, sums, batch);

    const int yChunks = 8;
    int jChunk = ((batch + yChunks * 64 - 1) / (yChunks * 64)) * 64;
    dim3 cg((batch + 63) / 64, yChunks, 2);
    closs_kernel<<<cg, 256, 0, stream>>>(pos1, aug1, pos2, aug2, S, Dg, batch, jChunk);
    closs_finish<<<1, 256, 0, stream>>>(S, Dg, sums, (float*)d_out, batch,
                                        1.0f / (float)batch);
}